// Round 17
// baseline (866.381 us; speedup 1.0000x reference)
//
#include <hip/hip_runtime.h>

// ---------------- problem constants ----------------
#define CCH   256
#define HH    96
#define WW    96
#define HO    94
#define LL    8836        // 94*94 patches
#define DD    2304        // 256*9 bytes per patch row (i8)
#define LPAD  8960        // 70 * 128 = 35 * 256
#define NPIX  9216        // 96*96

// GEMM: 128x256 block tile, 8 waves (2M x 4N), wave tile 64x64, i8 K=64 MFMA.
// K in 36 slices of 64 B/row; LDS ring-3 of (A 8KB + B 16KB) = 72 KiB.
// 2 blocks/CU; ONE barrier per slice; counted vmcnt(3).  [R14: 273 us]
#define NTI   70          // M tiles (8960/128)
#define NTJ   35          // N tiles (8960/256)
#define NPH   36          // 2304/64
#define SLTB  24576       // bytes per ring slot (A 8192 + B 16384)

typedef unsigned char u8;
typedef unsigned int u32;
typedef unsigned long long u64;

using i32x4 = __attribute__((ext_vector_type(4))) int;

// ---------------- workspace layout (bytes) ----------------
#define OFF_BQ    20643840ull
#define OFF_RNB   41287680ull
#define OFF_N2B   41323520ull
#define OFF_W2X   41359360ull
#define OFF_QSA   41395200ull
#define OFF_QSB   41431040ull
#define OFF_COLS  41466880ull
#define OFF_SAF   41502720ull
#define OFF_P2    41538560ull
#define OFF_PM    41612288ull
#define OFF_BEST  41686016ull
#define OFF_CNT   41758720ull

__device__ __forceinline__ void gload16(const void* g, void* l) {
    __builtin_amdgcn_global_load_lds(
        (const __attribute__((address_space(1))) unsigned int*)g,
        (__attribute__((address_space(3))) unsigned int*)l,
        16, 0, 0);
}

// ---- 1: per-pixel channel sum-of-squares and abs-max for both images ----
__global__ __launch_bounds__(256) void k_chan_stats(const float* __restrict__ st,
                                                    const float* __restrict__ x,
                                                    float* __restrict__ P2,
                                                    float* __restrict__ PM) {
    __shared__ float s2[8][32], sm[8][32];
    const int pix = threadIdx.x & 31, cg = threadIdx.x >> 5;
    const int pglob = blockIdx.x * 32;
    const bool isX = pglob >= NPIX;
    const float* img = isX ? x : st;
    const int pp = (isX ? pglob - NPIX : pglob) + pix;
    float s = 0.f, m = 0.f;
    const float* base = img + (size_t)(cg * 32) * NPIX + pp;
#pragma unroll 8
    for (int c = 0; c < 32; ++c) {
        float v = base[c * NPIX];
        s += v * v;
        m = fmaxf(m, fabsf(v));
    }
    s2[cg][pix] = s;
    sm[cg][pix] = m;
    __syncthreads();
    if (cg == 0) {
        float S = s, M = m;
#pragma unroll
        for (int g = 1; g < 8; ++g) {
            S += s2[g][pix];
            M = fmaxf(M, sm[g][pix]);
        }
        P2[pglob + pix] = S;
        PM[pglob + pix] = M;
    }
}

// ---- 2: 3x3 window reductions -> norms, quantizer scales; init best/out ----
__global__ __launch_bounds__(256) void k_win(const float* __restrict__ P2,
                                             const float* __restrict__ PM,
                                             float* __restrict__ rnB,
                                             float* __restrict__ n2B,
                                             float* __restrict__ win2x,
                                             float* __restrict__ qsA,
                                             float* __restrict__ qsB,
                                             float* __restrict__ colS,
                                             float* __restrict__ sAf,
                                             u64* __restrict__ best,
                                             u32* __restrict__ cnt,
                                             float* __restrict__ out) {
    int i = blockIdx.x * 256 + threadIdx.x;
    if (i >= LL) return;
    if (i == 0) { *out = 0.f; *cnt = 0u; }
    best[i] = 0;
    int y = i / HO, xc = i % HO;
    float ss = 0.f, sx = 0.f, ms = 0.f, mx = 0.f;
#pragma unroll
    for (int kh = 0; kh < 3; ++kh)
#pragma unroll
        for (int kw = 0; kw < 3; ++kw) {
            int off = (y + kh) * WW + xc + kw;
            ss += P2[off];
            sx += P2[NPIX + off];
            ms = fmaxf(ms, PM[off]);
            mx = fmaxf(mx, PM[NPIX + off]);
        }
    float rn = 1.f / (sqrtf(ss) + 1e-8f);
    float msc = fmaxf(ms, 1e-30f), mxc = fmaxf(mx, 1e-30f);
    rnB[i] = rn;
    n2B[i] = ss;
    win2x[i] = sx;
    qsA[i] = 127.f / mxc;
    qsB[i] = 127.f / msc;
    colS[i] = rn * msc * (1.f / 127.f);
    sAf[i] = mxc * (1.f / 127.f);
}

// ---- 3: quantize patches to i8, LDS-transposed for coalesced output ----
__global__ __launch_bounds__(512) void k_pack(const float* __restrict__ x,
                                              const float* __restrict__ st,
                                              const float* __restrict__ qsA,
                                              const float* __restrict__ qsB,
                                              u8* __restrict__ Aq,
                                              u8* __restrict__ Bq) {
    extern __shared__ u8 plds[];   // 47 * 2304 = 108288 bytes

    const int b = blockIdx.x;
    const int side = b & 1;            // 0 = A (x), 1 = B (style)
    const int half = (b >> 1) & 1;     // xc0 = half * 47
    const int y = b >> 2;              // 0..93
    const int xc0 = half * 47;

    const float* src = side ? st : x;
    const float* qs  = side ? qsB : qsA;
    u8* dst = (side ? Bq : Aq) + (size_t)(y * HO + xc0) * DD;

    const int t = threadIdx.x;
    if (t < 47 * 9) {
        const int il = t / 9, k = t - il * 9;
        const int kh = k / 3, kw = k - kh * 3;
        const int i = y * HO + xc0 + il;
        const float scale = qs[i];
        const float* sp = src + (y + kh) * WW + (xc0 + il + kw);
        u8* lp = plds + il * DD + k;
#pragma unroll 8
        for (int c = 0; c < CCH; ++c) {
            int qv = (int)rintf(sp[c * (HH * WW)] * scale);
            lp[c * 9] = (u8)qv;
        }
    }
    __syncthreads();
    for (int idx = t; idx < 6768; idx += 512) {
        *(i32x4*)(dst + idx * 16) = *(const i32x4*)(plds + idx * 16);
    }
}

// ---- 4: fused i8 GEMM + argmax + (last block) final MSE reduction ----
__global__ __launch_bounds__(512, 4) void k_gemm2(const u8* __restrict__ A,
                                                  const u8* __restrict__ Bm,
                                                  const float* __restrict__ colS,
                                                  const float* __restrict__ rnB,
                                                  const float* __restrict__ n2B,
                                                  const float* __restrict__ win2x,
                                                  const float* __restrict__ sAf,
                                                  u64* __restrict__ best,
                                                  u32* __restrict__ cnt,
                                                  float* __restrict__ out) {
    extern __shared__ __align__(16) u8 lds[];  // 3 x 24576 = 73728 B

    const int t = threadIdx.x;
    const int wid = t >> 6, lane = t & 63;
    const int wr = wid >> 2, wc = wid & 3;
    const int l15 = lane & 15, l4 = lane >> 4;

    // T1: bijective XCD swizzle (m204), nwg = 2450 (q=306, r=2)
    const int nwg = NTI * NTJ;
    const int q = nwg >> 3, r = nwg & 7;
    const int bid = blockIdx.x;
    const int xcd = bid & 7, loc = bid >> 3;
    const int swz = ((xcd < r) ? xcd * (q + 1) : r * (q + 1) + (xcd - r) * q) + loc;
    const int it = swz / NTJ, jt = swz % NTJ;

    // staging sources (pre-swizzled 16B k-group: (t&3)^((t>>3)&3))
    const int gsrc = (t & 3) ^ ((t >> 3) & 3);
    const u8* srcA = A  + (size_t)(it * 128 + (t >> 2)) * DD + gsrc * 16;
    const u8* srcB = Bm + (size_t)(jt * 256 + (t >> 2)) * DD + gsrc * 16;

    // fragment read offsets (swizzled): phys 16B-group = l4 ^ ((row>>1)&3)
    const int sp16 = (l4 ^ ((l15 >> 1) & 3)) * 16;
    int aoff[4], boff[4];
#pragma unroll
    for (int mi = 0; mi < 4; ++mi)
        aoff[mi] = (wr * 64 + mi * 16 + l15) * 64 + sp16;
#pragma unroll
    for (int ni = 0; ni < 4; ++ni)
        boff[ni] = 8192 + (wc * 64 + ni * 16 + l15) * 64 + sp16;

    i32x4 acc[4][4];
#pragma unroll
    for (int mi = 0; mi < 4; ++mi)
#pragma unroll
        for (int ni = 0; ni < 4; ++ni)
            acc[mi][ni] = (i32x4){0, 0, 0, 0};

    i32x4 af[4], bf[4];

#define STAGE(SS, SP)                                                        \
    do {                                                                     \
        const int sc_ = ((SS) > NPH - 1) ? (NPH - 1) : (SS);                 \
        const u8* sa = srcA + (size_t)sc_ * 64;                              \
        const u8* sb = srcB + (size_t)sc_ * 64;                              \
        u8* d = lds + (SP) * SLTB + t * 16;                                  \
        gload16(sa, d);                                                      \
        gload16(sb, d + 8192);                                               \
        gload16(sb + 128 * DD, d + 16384);                                   \
    } while (0)

    // prologue: stage slices 0,1; wait slice 0 (counted: slice 1 in flight)
    STAGE(0, 0);
    STAGE(1, 1);
    asm volatile("s_waitcnt vmcnt(3)" ::: "memory");
    __builtin_amdgcn_sched_barrier(0);
    __builtin_amdgcn_s_barrier();

// BODY(S,SC): ONE barrier per slice. Read frags(S) from slot SC; stage S+2
// into slot (SC+2)%3; lgkm(0) -> MFMA; vmcnt(3) -> barrier.
#define BODY(S, SC)                                                          \
    {                                                                        \
        _Pragma("unroll")                                                    \
        for (int ni = 0; ni < 4; ++ni)                                       \
            bf[ni] = *(const i32x4*)(lds + (SC) * SLTB + boff[ni]);          \
        _Pragma("unroll")                                                    \
        for (int mi = 0; mi < 4; ++mi)                                       \
            af[mi] = *(const i32x4*)(lds + (SC) * SLTB + aoff[mi]);          \
        STAGE((S) + 2, ((SC) + 2) % 3);                                      \
        asm volatile("s_waitcnt lgkmcnt(0)" ::: "memory");                   \
        __builtin_amdgcn_sched_barrier(0);                                   \
        __builtin_amdgcn_s_setprio(1);                                       \
        _Pragma("unroll")                                                    \
        for (int mi = 0; mi < 4; ++mi)                                       \
            _Pragma("unroll")                                                \
            for (int ni = 0; ni < 4; ++ni)                                   \
                acc[mi][ni] = __builtin_amdgcn_mfma_i32_16x16x64_i8(         \
                    af[mi], bf[ni], acc[mi][ni], 0, 0, 0);                   \
        __builtin_amdgcn_s_setprio(0);                                       \
        asm volatile("s_waitcnt vmcnt(3)" ::: "memory");                     \
        __builtin_amdgcn_sched_barrier(0);                                   \
        __builtin_amdgcn_s_barrier();                                        \
    }

    for (int s3 = 0; s3 < NPH; s3 += 3) {
        BODY(s3,     0)
        BODY(s3 + 1, 1)
        BODY(s3 + 2, 2)
    }
#undef BODY
#undef STAGE

    // epilogue: per output row, argmax of (int dot * colS_j) over 256 j's
    const int jbase = jt * 256 + wc * 64 + l15;
    float cs[4];
#pragma unroll
    for (int ni = 0; ni < 4; ++ni) {
        int j = jbase + ni * 16;
        cs[ni] = colS[j < LL ? j : 0];
    }
#pragma unroll
    for (int mi = 0; mi < 4; ++mi) {
#pragma unroll
        for (int rr = 0; rr < 4; ++rr) {
            float bv = -3.4e38f;
            int bj = 0x7FFFFFFF;
#pragma unroll
            for (int ni = 0; ni < 4; ++ni) {
                int j = jbase + ni * 16;
                float v = (float)acc[mi][ni][rr] * cs[ni];
                if (j < LL && (v > bv || (v == bv && j < bj))) { bv = v; bj = j; }
            }
#pragma unroll
            for (int m = 1; m < 16; m <<= 1) {
                float ov = __shfl_xor(bv, m, 64);
                int oj = __shfl_xor(bj, m, 64);
                if (ov > bv || (ov == bv && oj < bj)) { bv = ov; bj = oj; }
            }
            if (l15 == 0) {
                int i = it * 128 + wr * 64 + mi * 16 + l4 * 4 + rr;
                if (i < LL) {
                    unsigned u = __float_as_uint(bv);
                    unsigned s = (bv < 0.f) ? ~u : (u | 0x80000000u);
                    u64 packed = ((u64)s << 32) | (unsigned)(~(unsigned)bj);
                    atomicMax(&best[i], packed);
                }
            }
        }
    }

    // ---- folded final: last block to finish computes the MSE scalar ----
    __threadfence();
    __syncthreads();                 // all 512 threads' atomicMax done+fenced
    u32* dflag = (u32*)lds;          // reuse LDS (loop is over)
    float* red = (float*)(lds + 64);
    if (t == 0) dflag[0] = atomicAdd(cnt, 1u);
    __syncthreads();
    if (dflag[0] == (u32)(nwg - 1)) {
        float part = 0.f;
        for (int i = t; i < LL; i += 512) {
            u64 p = __hip_atomic_load(&best[i], __ATOMIC_RELAXED,
                                      __HIP_MEMORY_SCOPE_AGENT);
            unsigned s = (unsigned)(p >> 32);
            unsigned ub = (s & 0x80000000u) ? (s & 0x7FFFFFFFu) : ~s;
            float bv = __uint_as_float(ub);
            int j = (int)(~(unsigned)(p & 0xFFFFFFFFull));
            float dot = (bv * sAf[i]) / rnB[j];
            part += win2x[i] + n2B[j] - 2.f * dot;
        }
#pragma unroll
        for (int o = 32; o > 0; o >>= 1) part += __shfl_down(part, o, 64);
        if (lane == 0) red[wid] = part;
        __syncthreads();
        if (t == 0) {
            float tot = 0.f;
#pragma unroll
            for (int w = 0; w < 8; ++w) tot += red[w];
            *out = tot * (1.0f / ((float)DD * (float)LL));
        }
    }
}

extern "C" void kernel_launch(void* const* d_in, const int* in_sizes, int n_in,
                              void* d_out, int out_size, void* d_ws, size_t ws_size,
                              hipStream_t stream) {
    const float* x  = (const float*)d_in[0];
    const float* st = (const float*)d_in[1];
    char* ws = (char*)d_ws;

    u8* Aq       = (u8*)ws;
    u8* Bq       = (u8*)(ws + OFF_BQ);
    float* rnB   = (float*)(ws + OFF_RNB);
    float* n2B   = (float*)(ws + OFF_N2B);
    float* win2x = (float*)(ws + OFF_W2X);
    float* qsA   = (float*)(ws + OFF_QSA);
    float* qsB   = (float*)(ws + OFF_QSB);
    float* colS  = (float*)(ws + OFF_COLS);
    float* sAf   = (float*)(ws + OFF_SAF);
    float* P2    = (float*)(ws + OFF_P2);
    float* PM    = (float*)(ws + OFF_PM);
    u64* best    = (u64*)(ws + OFF_BEST);
    u32* cnt     = (u32*)(ws + OFF_CNT);
    float* out   = (float*)d_out;

    hipFuncSetAttribute((const void*)k_gemm2,
                        hipFuncAttributeMaxDynamicSharedMemorySize, 73728);
    hipFuncSetAttribute((const void*)k_pack,
                        hipFuncAttributeMaxDynamicSharedMemorySize, 110592);

    k_chan_stats<<<dim3(2 * NPIX / 32), dim3(256), 0, stream>>>(st, x, P2, PM);
    k_win<<<dim3(35), dim3(256), 0, stream>>>(P2, PM, rnB, n2B, win2x,
                                              qsA, qsB, colS, sAf, best, cnt, out);
    k_pack<<<dim3(HO * 4), dim3(512), 108288, stream>>>(x, st, qsA, qsB, Aq, Bq);
    k_gemm2<<<dim3(NTI * NTJ), dim3(512), 73728, stream>>>(Aq, Bq, colS,
                                                           rnB, n2B, win2x, sAf,
                                                           best, cnt, out);
}

// Round 18
// 331.720 us; speedup vs baseline: 2.6118x; 2.6118x over previous
//
#include <hip/hip_runtime.h>

// ---------------- problem constants ----------------
#define CCH   256
#define HH    96
#define WW    96
#define HO    94
#define LL    8836        // 94*94 patches
#define DD    2304        // 256*9 bytes per patch row (i8)
#define LPAD  8960        // 70 * 128 = 35 * 256
#define NPIX  9216        // 96*96

// GEMM: 128x256 block tile, 8 waves (2M x 4N), wave tile 64x64, i8 K=64 MFMA.
// K in 36 slices of 64 B/row; LDS ring-3 of (A 8KB + B 16KB) = 72 KiB.
// 2 blocks/CU; ONE barrier per slice; counted vmcnt(3).  [R14/R15: 273 us]
#define NTI   70          // M tiles (8960/128)
#define NTJ   35          // N tiles (8960/256)
#define NPH   36          // 2304/64
#define SLTB  24576       // bytes per ring slot (A 8192 + B 16384)

typedef unsigned char u8;
typedef unsigned long long u64;

using i32x4 = __attribute__((ext_vector_type(4))) int;

// ---------------- workspace layout (bytes) ----------------
#define OFF_BQ    20643840ull
#define OFF_RNB   41287680ull
#define OFF_N2B   41323520ull
#define OFF_W2X   41359360ull
#define OFF_QSA   41395200ull
#define OFF_QSB   41431040ull
#define OFF_COLS  41466880ull
#define OFF_SAF   41502720ull
#define OFF_P2    41538560ull
#define OFF_PM    41612288ull
#define OFF_BEST  41686016ull

__device__ __forceinline__ void gload16(const void* g, void* l) {
    __builtin_amdgcn_global_load_lds(
        (const __attribute__((address_space(1))) unsigned int*)g,
        (__attribute__((address_space(3))) unsigned int*)l,
        16, 0, 0);
}

// ---- 1: per-pixel channel sum-of-squares and abs-max for both images ----
// 576 blocks x 256 threads: 32 pixels x 8 channel-groups, LDS reduce.
__global__ __launch_bounds__(256) void k_chan_stats(const float* __restrict__ st,
                                                    const float* __restrict__ x,
                                                    float* __restrict__ P2,
                                                    float* __restrict__ PM) {
    __shared__ float s2[8][32], sm[8][32];
    const int pix = threadIdx.x & 31, cg = threadIdx.x >> 5;
    const int pglob = blockIdx.x * 32;
    const bool isX = pglob >= NPIX;
    const float* img = isX ? x : st;
    const int pp = (isX ? pglob - NPIX : pglob) + pix;
    float s = 0.f, m = 0.f;
    const float* base = img + (size_t)(cg * 32) * NPIX + pp;
#pragma unroll 8
    for (int c = 0; c < 32; ++c) {
        float v = base[c * NPIX];
        s += v * v;
        m = fmaxf(m, fabsf(v));
    }
    s2[cg][pix] = s;
    sm[cg][pix] = m;
    __syncthreads();
    if (cg == 0) {
        float S = s, M = m;
#pragma unroll
        for (int g = 1; g < 8; ++g) {
            S += s2[g][pix];
            M = fmaxf(M, sm[g][pix]);
        }
        P2[pglob + pix] = S;
        PM[pglob + pix] = M;
    }
}

// ---- 2: 3x3 window reductions -> norms, quantizer scales; init best/out ----
__global__ __launch_bounds__(256) void k_win(const float* __restrict__ P2,
                                             const float* __restrict__ PM,
                                             float* __restrict__ rnB,
                                             float* __restrict__ n2B,
                                             float* __restrict__ win2x,
                                             float* __restrict__ qsA,
                                             float* __restrict__ qsB,
                                             float* __restrict__ colS,
                                             float* __restrict__ sAf,
                                             u64* __restrict__ best,
                                             float* __restrict__ out) {
    int i = blockIdx.x * 256 + threadIdx.x;
    if (i >= LL) return;
    if (i == 0) *out = 0.f;
    best[i] = 0;
    int y = i / HO, xc = i % HO;
    float ss = 0.f, sx = 0.f, ms = 0.f, mx = 0.f;
#pragma unroll
    for (int kh = 0; kh < 3; ++kh)
#pragma unroll
        for (int kw = 0; kw < 3; ++kw) {
            int off = (y + kh) * WW + xc + kw;
            ss += P2[off];
            sx += P2[NPIX + off];
            ms = fmaxf(ms, PM[off]);
            mx = fmaxf(mx, PM[NPIX + off]);
        }
    float rn = 1.f / (sqrtf(ss) + 1e-8f);
    float msc = fmaxf(ms, 1e-30f), mxc = fmaxf(mx, 1e-30f);
    rnB[i] = rn;
    n2B[i] = ss;
    win2x[i] = sx;
    qsA[i] = 127.f / mxc;
    qsB[i] = 127.f / msc;
    colS[i] = rn * msc * (1.f / 127.f);
    sAf[i] = mxc * (1.f / 127.f);
}

// ---- 3: quantize patches to i8, LDS-transposed for coalesced output ----
__global__ __launch_bounds__(512) void k_pack(const float* __restrict__ x,
                                              const float* __restrict__ st,
                                              const float* __restrict__ qsA,
                                              const float* __restrict__ qsB,
                                              u8* __restrict__ Aq,
                                              u8* __restrict__ Bq) {
    extern __shared__ u8 plds[];   // 47 * 2304 = 108288 bytes

    const int b = blockIdx.x;
    const int side = b & 1;            // 0 = A (x), 1 = B (style)
    const int half = (b >> 1) & 1;     // xc0 = half * 47
    const int y = b >> 2;              // 0..93
    const int xc0 = half * 47;

    const float* src = side ? st : x;
    const float* qs  = side ? qsB : qsA;
    u8* dst = (side ? Bq : Aq) + (size_t)(y * HO + xc0) * DD;

    const int t = threadIdx.x;
    if (t < 47 * 9) {
        const int il = t / 9, k = t - il * 9;
        const int kh = k / 3, kw = k - kh * 3;
        const int i = y * HO + xc0 + il;
        const float scale = qs[i];
        const float* sp = src + (y + kh) * WW + (xc0 + il + kw);
        u8* lp = plds + il * DD + k;
#pragma unroll 8
        for (int c = 0; c < CCH; ++c) {
            int qv = (int)rintf(sp[c * (HH * WW)] * scale);
            lp[c * 9] = (u8)qv;
        }
    }
    __syncthreads();
    for (int idx = t; idx < 6768; idx += 512) {
        *(i32x4*)(dst + idx * 16) = *(const i32x4*)(plds + idx * 16);
    }
}

// ---- 4: fused i8 GEMM (A * B^T) + per-row scaled argmax, 1 barrier/slice ----
__global__ __launch_bounds__(512, 4) void k_gemm2(const u8* __restrict__ A,
                                                  const u8* __restrict__ Bm,
                                                  const float* __restrict__ colS,
                                                  u64* __restrict__ best) {
    extern __shared__ __align__(16) u8 lds[];  // 3 x 24576 = 73728 B

    const int t = threadIdx.x;
    const int wid = t >> 6, lane = t & 63;
    const int wr = wid >> 2, wc = wid & 3;
    const int l15 = lane & 15, l4 = lane >> 4;

    // T1: bijective XCD swizzle (m204), nwg = 2450 (q=306, r=2)
    const int nwg = NTI * NTJ;
    const int q = nwg >> 3, r = nwg & 7;
    const int bid = blockIdx.x;
    const int xcd = bid & 7, loc = bid >> 3;
    const int swz = ((xcd < r) ? xcd * (q + 1) : r * (q + 1) + (xcd - r) * q) + loc;
    const int it = swz / NTJ, jt = swz % NTJ;

    // staging sources (pre-swizzled 16B k-group: (t&3)^((t>>3)&3))
    const int gsrc = (t & 3) ^ ((t >> 3) & 3);
    const u8* srcA = A  + (size_t)(it * 128 + (t >> 2)) * DD + gsrc * 16;
    const u8* srcB = Bm + (size_t)(jt * 256 + (t >> 2)) * DD + gsrc * 16;

    // fragment read offsets (swizzled): phys 16B-group = l4 ^ ((row>>1)&3)
    const int sp16 = (l4 ^ ((l15 >> 1) & 3)) * 16;
    int aoff[4], boff[4];
#pragma unroll
    for (int mi = 0; mi < 4; ++mi)
        aoff[mi] = (wr * 64 + mi * 16 + l15) * 64 + sp16;
#pragma unroll
    for (int ni = 0; ni < 4; ++ni)
        boff[ni] = 8192 + (wc * 64 + ni * 16 + l15) * 64 + sp16;

    i32x4 acc[4][4];
#pragma unroll
    for (int mi = 0; mi < 4; ++mi)
#pragma unroll
        for (int ni = 0; ni < 4; ++ni)
            acc[mi][ni] = (i32x4){0, 0, 0, 0};

    i32x4 af[4], bf[4];

#define STAGE(SS, SP)                                                        \
    do {                                                                     \
        const int sc_ = ((SS) > NPH - 1) ? (NPH - 1) : (SS);                 \
        const u8* sa = srcA + (size_t)sc_ * 64;                              \
        const u8* sb = srcB + (size_t)sc_ * 64;                              \
        u8* d = lds + (SP) * SLTB + t * 16;                                  \
        gload16(sa, d);                                                      \
        gload16(sb, d + 8192);                                               \
        gload16(sb + 128 * DD, d + 16384);                                   \
    } while (0)

    // prologue: stage slices 0,1; wait slice 0 (counted: slice 1 in flight)
    STAGE(0, 0);
    STAGE(1, 1);
    asm volatile("s_waitcnt vmcnt(3)" ::: "memory");
    __builtin_amdgcn_sched_barrier(0);
    __builtin_amdgcn_s_barrier();

// BODY(S,SC): ONE barrier per slice. Read frags(S) from slot SC; stage S+2
// into slot (SC+2)%3 (overwrites slice S-1, whose reads completed before the
// previous barrier); lgkm(0) -> MFMA; vmcnt(3) (S+1 landed) -> barrier.
#define BODY(S, SC)                                                          \
    {                                                                        \
        _Pragma("unroll")                                                    \
        for (int ni = 0; ni < 4; ++ni)                                       \
            bf[ni] = *(const i32x4*)(lds + (SC) * SLTB + boff[ni]);          \
        _Pragma("unroll")                                                    \
        for (int mi = 0; mi < 4; ++mi)                                       \
            af[mi] = *(const i32x4*)(lds + (SC) * SLTB + aoff[mi]);          \
        STAGE((S) + 2, ((SC) + 2) % 3);                                      \
        asm volatile("s_waitcnt lgkmcnt(0)" ::: "memory");                   \
        __builtin_amdgcn_sched_barrier(0);                                   \
        __builtin_amdgcn_s_setprio(1);                                       \
        _Pragma("unroll")                                                    \
        for (int mi = 0; mi < 4; ++mi)                                       \
            _Pragma("unroll")                                                \
            for (int ni = 0; ni < 4; ++ni)                                   \
                acc[mi][ni] = __builtin_amdgcn_mfma_i32_16x16x64_i8(         \
                    af[mi], bf[ni], acc[mi][ni], 0, 0, 0);                   \
        __builtin_amdgcn_s_setprio(0);                                       \
        asm volatile("s_waitcnt vmcnt(3)" ::: "memory");                     \
        __builtin_amdgcn_sched_barrier(0);                                   \
        __builtin_amdgcn_s_barrier();                                        \
    }

    for (int s3 = 0; s3 < NPH; s3 += 3) {
        BODY(s3,     0)
        BODY(s3 + 1, 1)
        BODY(s3 + 2, 2)
    }
#undef BODY
#undef STAGE

    // epilogue: per output row, argmax of (int dot * colS_j) over 256 j's
    const int jbase = jt * 256 + wc * 64 + l15;
    float cs[4];
#pragma unroll
    for (int ni = 0; ni < 4; ++ni) {
        int j = jbase + ni * 16;
        cs[ni] = colS[j < LL ? j : 0];
    }
#pragma unroll
    for (int mi = 0; mi < 4; ++mi) {
#pragma unroll
        for (int rr = 0; rr < 4; ++rr) {
            float bv = -3.4e38f;
            int bj = 0x7FFFFFFF;
#pragma unroll
            for (int ni = 0; ni < 4; ++ni) {
                int j = jbase + ni * 16;
                float v = (float)acc[mi][ni][rr] * cs[ni];
                if (j < LL && (v > bv || (v == bv && j < bj))) { bv = v; bj = j; }
            }
#pragma unroll
            for (int m = 1; m < 16; m <<= 1) {
                float ov = __shfl_xor(bv, m, 64);
                int oj = __shfl_xor(bj, m, 64);
                if (ov > bv || (ov == bv && oj < bj)) { bv = ov; bj = oj; }
            }
            if (l15 == 0) {
                int i = it * 128 + wr * 64 + mi * 16 + l4 * 4 + rr;
                if (i < LL) {
                    unsigned u = __float_as_uint(bv);
                    unsigned s = (bv < 0.f) ? ~u : (u | 0x80000000u);
                    u64 packed = ((u64)s << 32) | (unsigned)(~(unsigned)bj);
                    atomicMax(&best[i], packed);
                }
            }
        }
    }
}

// ---- 5: final scalar ----
__global__ __launch_bounds__(256) void k_final(const u64* __restrict__ best,
                                               const float* __restrict__ rnB,
                                               const float* __restrict__ n2B,
                                               const float* __restrict__ win2x,
                                               const float* __restrict__ sAf,
                                               float* __restrict__ out) {
    int i = blockIdx.x * 256 + threadIdx.x;
    float contrib = 0.f;
    if (i < LL) {
        u64 p = best[i];
        unsigned s = (unsigned)(p >> 32);
        unsigned ub = (s & 0x80000000u) ? (s & 0x7FFFFFFFu) : ~s;
        float bv = __uint_as_float(ub);
        int j = (int)(~(unsigned)(p & 0xFFFFFFFFull));
        float dot = (bv * sAf[i]) / rnB[j];
        contrib = win2x[i] + n2B[j] - 2.f * dot;
    }
    float sred = contrib;
#pragma unroll
    for (int o = 32; o > 0; o >>= 1) sred += __shfl_down(sred, o, 64);
    __shared__ float red[4];
    if ((threadIdx.x & 63) == 0) red[threadIdx.x >> 6] = sred;
    __syncthreads();
    if (threadIdx.x == 0) {
        float tot = red[0] + red[1] + red[2] + red[3];
        atomicAdd(out, tot * (1.0f / ((float)DD * (float)LL)));
    }
}

extern "C" void kernel_launch(void* const* d_in, const int* in_sizes, int n_in,
                              void* d_out, int out_size, void* d_ws, size_t ws_size,
                              hipStream_t stream) {
    const float* x  = (const float*)d_in[0];
    const float* st = (const float*)d_in[1];
    char* ws = (char*)d_ws;

    u8* Aq       = (u8*)ws;
    u8* Bq       = (u8*)(ws + OFF_BQ);
    float* rnB   = (float*)(ws + OFF_RNB);
    float* n2B   = (float*)(ws + OFF_N2B);
    float* win2x = (float*)(ws + OFF_W2X);
    float* qsA   = (float*)(ws + OFF_QSA);
    float* qsB   = (float*)(ws + OFF_QSB);
    float* colS  = (float*)(ws + OFF_COLS);
    float* sAf   = (float*)(ws + OFF_SAF);
    float* P2    = (float*)(ws + OFF_P2);
    float* PM    = (float*)(ws + OFF_PM);
    u64* best    = (u64*)(ws + OFF_BEST);
    float* out   = (float*)d_out;

    hipFuncSetAttribute((const void*)k_gemm2,
                        hipFuncAttributeMaxDynamicSharedMemorySize, 73728);
    hipFuncSetAttribute((const void*)k_pack,
                        hipFuncAttributeMaxDynamicSharedMemorySize, 110592);

    k_chan_stats<<<dim3(2 * NPIX / 32), dim3(256), 0, stream>>>(st, x, P2, PM);
    k_win<<<dim3(35), dim3(256), 0, stream>>>(P2, PM, rnB, n2B, win2x,
                                              qsA, qsB, colS, sAf, best, out);
    k_pack<<<dim3(HO * 4), dim3(512), 108288, stream>>>(x, st, qsA, qsB, Aq, Bq);
    k_gemm2<<<dim3(NTI * NTJ), dim3(512), 73728, stream>>>(Aq, Bq, colS, best);
    k_final<<<dim3(35), dim3(256), 0, stream>>>(best, rnB, n2B, win2x, sAf, out);
}

// Round 19
// 326.980 us; speedup vs baseline: 2.6496x; 1.0145x over previous
//
#include <hip/hip_runtime.h>

// ---------------- problem constants ----------------
#define CCH   256
#define HH    96
#define WW    96
#define HO    94
#define LL    8836        // 94*94 patches
#define DD    2304        // 256*9 bytes per patch row (i8)
#define LPAD  8960        // 70 * 128 = 35 * 256
#define NPIX  9216        // 96*96

// GEMM: 128x256 block tile, 8 waves (2M x 4N), wave tile 64x64, i8 K=64 MFMA.
// K in 36 slices of 64 B/row; LDS ring-3 of (A 8KB + B 16KB) = 72 KiB.
// 2 blocks/CU; ONE barrier per slice; counted vmcnt(3).  [R18: 267 us]
#define NTI   70          // M tiles (8960/128)
#define NTJ   35          // N tiles (8960/256)
#define NPH   36          // 2304/64
#define SLTB  24576       // bytes per ring slot (A 8192 + B 16384)

typedef unsigned char u8;
typedef unsigned long long u64;

using i32x4 = __attribute__((ext_vector_type(4))) int;

// ---------------- workspace layout (bytes) ----------------
#define OFF_BQ    20643840ull
#define OFF_RNB   41287680ull
#define OFF_N2B   41323520ull
#define OFF_W2X   41359360ull
#define OFF_COLS  41466880ull
#define OFF_SAF   41502720ull
#define OFF_P2    41538560ull
#define OFF_PM    41612288ull
#define OFF_BEST  41686016ull

__device__ __forceinline__ void gload16(const void* g, void* l) {
    __builtin_amdgcn_global_load_lds(
        (const __attribute__((address_space(1))) unsigned int*)g,
        (__attribute__((address_space(3))) unsigned int*)l,
        16, 0, 0);
}

// ---- 1: per-pixel channel sum-of-squares / abs-max; init best + out ----
// 576 blocks x 256 threads: 32 pixels x 8 channel-groups, LDS reduce.
__global__ __launch_bounds__(256) void k_chan_stats(const float* __restrict__ st,
                                                    const float* __restrict__ x,
                                                    float* __restrict__ P2,
                                                    float* __restrict__ PM,
                                                    u64* __restrict__ best,
                                                    float* __restrict__ out) {
    __shared__ float s2[8][32], sm[8][32];
    const int gid = blockIdx.x * 256 + threadIdx.x;
    if (gid < LL) best[gid] = 0;
    if (gid == 0) *out = 0.f;
    const int pix = threadIdx.x & 31, cg = threadIdx.x >> 5;
    const int pglob = blockIdx.x * 32;
    const bool isX = pglob >= NPIX;
    const float* img = isX ? x : st;
    const int pp = (isX ? pglob - NPIX : pglob) + pix;
    float s = 0.f, m = 0.f;
    const float* base = img + (size_t)(cg * 32) * NPIX + pp;
#pragma unroll 8
    for (int c = 0; c < 32; ++c) {
        float v = base[c * NPIX];
        s += v * v;
        m = fmaxf(m, fabsf(v));
    }
    s2[cg][pix] = s;
    sm[cg][pix] = m;
    __syncthreads();
    if (cg == 0) {
        float S = s, M = m;
#pragma unroll
        for (int g = 1; g < 8; ++g) {
            S += s2[g][pix];
            M = fmaxf(M, sm[g][pix]);
        }
        P2[pglob + pix] = S;
        PM[pglob + pix] = M;
    }
}

// ---- 2: window reductions + quantize patches to i8 (k_win folded in) ----
// block = (y, half, side): 47 patches. First 47 threads compute the 3x3
// window stats for their patch, derive/write the per-patch outputs and the
// local quantizer scale; then 423 threads quantize; coalesced copy-out.
__global__ __launch_bounds__(512) void k_pack(const float* __restrict__ x,
                                              const float* __restrict__ st,
                                              const float* __restrict__ P2,
                                              const float* __restrict__ PM,
                                              float* __restrict__ rnB,
                                              float* __restrict__ n2B,
                                              float* __restrict__ win2x,
                                              float* __restrict__ colS,
                                              float* __restrict__ sAf,
                                              u8* __restrict__ Aq,
                                              u8* __restrict__ Bq) {
    extern __shared__ u8 plds[];   // 47*2304 codes + 47 scales = 108480 B

    const int b = blockIdx.x;
    const int side = b & 1;            // 0 = A (x), 1 = B (style)
    const int half = (b >> 1) & 1;     // xc0 = half * 47
    const int y = b >> 2;              // 0..93
    const int xc0 = half * 47;

    const float* src = side ? st : x;
    u8* dst = (side ? Bq : Aq) + (size_t)(y * HO + xc0) * DD;
    float* sc = (float*)(plds + 47 * DD);

    const int t = threadIdx.x;
    if (t < 47) {
        const int i = y * HO + xc0 + t;
        float ss = 0.f, sx = 0.f, ms = 0.f, mx = 0.f;
#pragma unroll
        for (int kh = 0; kh < 3; ++kh)
#pragma unroll
            for (int kw = 0; kw < 3; ++kw) {
                int off = (y + kh) * WW + xc0 + t + kw;
                ss += P2[off];
                sx += P2[NPIX + off];
                ms = fmaxf(ms, PM[off]);
                mx = fmaxf(mx, PM[NPIX + off]);
            }
        float msc = fmaxf(ms, 1e-30f), mxc = fmaxf(mx, 1e-30f);
        if (side) {   // style-side outputs
            float rn = 1.f / (sqrtf(ss) + 1e-8f);
            rnB[i] = rn;
            n2B[i] = ss;
            colS[i] = rn * msc * (1.f / 127.f);
            sc[t] = 127.f / msc;
        } else {      // x-side outputs
            win2x[i] = sx;
            sAf[i] = mxc * (1.f / 127.f);
            sc[t] = 127.f / mxc;
        }
    }
    __syncthreads();
    if (t < 47 * 9) {
        const int il = t / 9, k = t - il * 9;
        const int kh = k / 3, kw = k - kh * 3;
        const float scale = sc[il];
        const float* sp = src + (y + kh) * WW + (xc0 + il + kw);
        u8* lp = plds + il * DD + k;
#pragma unroll 8
        for (int c = 0; c < CCH; ++c) {
            int qv = (int)rintf(sp[c * NPIX] * scale);
            lp[c * 9] = (u8)qv;
        }
    }
    __syncthreads();
    for (int idx = t; idx < 6768; idx += 512) {
        *(i32x4*)(dst + idx * 16) = *(const i32x4*)(plds + idx * 16);
    }
}

// ---- 3: fused i8 GEMM (A * B^T) + per-row scaled argmax, 1 barrier/slice ----
__global__ __launch_bounds__(512, 4) void k_gemm2(const u8* __restrict__ A,
                                                  const u8* __restrict__ Bm,
                                                  const float* __restrict__ colS,
                                                  u64* __restrict__ best) {
    extern __shared__ __align__(16) u8 lds[];  // 3 x 24576 = 73728 B

    const int t = threadIdx.x;
    const int wid = t >> 6, lane = t & 63;
    const int wr = wid >> 2, wc = wid & 3;
    const int l15 = lane & 15, l4 = lane >> 4;

    // T1: bijective XCD swizzle (m204), nwg = 2450 (q=306, r=2)
    const int nwg = NTI * NTJ;
    const int q = nwg >> 3, r = nwg & 7;
    const int bid = blockIdx.x;
    const int xcd = bid & 7, loc = bid >> 3;
    const int swz = ((xcd < r) ? xcd * (q + 1) : r * (q + 1) + (xcd - r) * q) + loc;
    const int it = swz / NTJ, jt = swz % NTJ;

    // staging sources (pre-swizzled 16B k-group: (t&3)^((t>>3)&3))
    const int gsrc = (t & 3) ^ ((t >> 3) & 3);
    const u8* srcA = A  + (size_t)(it * 128 + (t >> 2)) * DD + gsrc * 16;
    const u8* srcB = Bm + (size_t)(jt * 256 + (t >> 2)) * DD + gsrc * 16;

    // fragment read offsets (swizzled): phys 16B-group = l4 ^ ((row>>1)&3)
    const int sp16 = (l4 ^ ((l15 >> 1) & 3)) * 16;
    int aoff[4], boff[4];
#pragma unroll
    for (int mi = 0; mi < 4; ++mi)
        aoff[mi] = (wr * 64 + mi * 16 + l15) * 64 + sp16;
#pragma unroll
    for (int ni = 0; ni < 4; ++ni)
        boff[ni] = 8192 + (wc * 64 + ni * 16 + l15) * 64 + sp16;

    i32x4 acc[4][4];
#pragma unroll
    for (int mi = 0; mi < 4; ++mi)
#pragma unroll
        for (int ni = 0; ni < 4; ++ni)
            acc[mi][ni] = (i32x4){0, 0, 0, 0};

    i32x4 af[4], bf[4];

#define STAGE(SS, SP)                                                        \
    do {                                                                     \
        const int sc_ = ((SS) > NPH - 1) ? (NPH - 1) : (SS);                 \
        const u8* sa = srcA + (size_t)sc_ * 64;                              \
        const u8* sb = srcB + (size_t)sc_ * 64;                              \
        u8* d = lds + (SP) * SLTB + t * 16;                                  \
        gload16(sa, d);                                                      \
        gload16(sb, d + 8192);                                               \
        gload16(sb + 128 * DD, d + 16384);                                   \
    } while (0)

    // prologue: stage slices 0,1; wait slice 0 (counted: slice 1 in flight)
    STAGE(0, 0);
    STAGE(1, 1);
    asm volatile("s_waitcnt vmcnt(3)" ::: "memory");
    __builtin_amdgcn_sched_barrier(0);
    __builtin_amdgcn_s_barrier();

// BODY(S,SC): ONE barrier per slice. Read frags(S) from slot SC; stage S+2
// into slot (SC+2)%3 (overwrites slice S-1, whose reads completed before the
// previous barrier); lgkm(0) -> MFMA; vmcnt(3) (S+1 landed) -> barrier.
#define BODY(S, SC)                                                          \
    {                                                                        \
        _Pragma("unroll")                                                    \
        for (int ni = 0; ni < 4; ++ni)                                       \
            bf[ni] = *(const i32x4*)(lds + (SC) * SLTB + boff[ni]);          \
        _Pragma("unroll")                                                    \
        for (int mi = 0; mi < 4; ++mi)                                       \
            af[mi] = *(const i32x4*)(lds + (SC) * SLTB + aoff[mi]);          \
        STAGE((S) + 2, ((SC) + 2) % 3);                                      \
        asm volatile("s_waitcnt lgkmcnt(0)" ::: "memory");                   \
        __builtin_amdgcn_sched_barrier(0);                                   \
        __builtin_amdgcn_s_setprio(1);                                       \
        _Pragma("unroll")                                                    \
        for (int mi = 0; mi < 4; ++mi)                                       \
            _Pragma("unroll")                                                \
            for (int ni = 0; ni < 4; ++ni)                                   \
                acc[mi][ni] = __builtin_amdgcn_mfma_i32_16x16x64_i8(         \
                    af[mi], bf[ni], acc[mi][ni], 0, 0, 0);                   \
        __builtin_amdgcn_s_setprio(0);                                       \
        asm volatile("s_waitcnt vmcnt(3)" ::: "memory");                     \
        __builtin_amdgcn_sched_barrier(0);                                   \
        __builtin_amdgcn_s_barrier();                                        \
    }

    for (int s3 = 0; s3 < NPH; s3 += 3) {
        BODY(s3,     0)
        BODY(s3 + 1, 1)
        BODY(s3 + 2, 2)
    }
#undef BODY
#undef STAGE

    // epilogue: per output row, argmax of (int dot * colS_j) over 256 j's
    const int jbase = jt * 256 + wc * 64 + l15;
    float cs[4];
#pragma unroll
    for (int ni = 0; ni < 4; ++ni) {
        int j = jbase + ni * 16;
        cs[ni] = colS[j < LL ? j : 0];
    }
#pragma unroll
    for (int mi = 0; mi < 4; ++mi) {
#pragma unroll
        for (int rr = 0; rr < 4; ++rr) {
            float bv = -3.4e38f;
            int bj = 0x7FFFFFFF;
#pragma unroll
            for (int ni = 0; ni < 4; ++ni) {
                int j = jbase + ni * 16;
                float v = (float)acc[mi][ni][rr] * cs[ni];
                if (j < LL && (v > bv || (v == bv && j < bj))) { bv = v; bj = j; }
            }
#pragma unroll
            for (int m = 1; m < 16; m <<= 1) {
                float ov = __shfl_xor(bv, m, 64);
                int oj = __shfl_xor(bj, m, 64);
                if (ov > bv || (ov == bv && oj < bj)) { bv = ov; bj = oj; }
            }
            if (l15 == 0) {
                int i = it * 128 + wr * 64 + mi * 16 + l4 * 4 + rr;
                if (i < LL) {
                    unsigned u = __float_as_uint(bv);
                    unsigned s = (bv < 0.f) ? ~u : (u | 0x80000000u);
                    u64 packed = ((u64)s << 32) | (unsigned)(~(unsigned)bj);
                    atomicMax(&best[i], packed);
                }
            }
        }
    }
}

// ---- 4: final scalar ----
__global__ __launch_bounds__(256) void k_final(const u64* __restrict__ best,
                                               const float* __restrict__ rnB,
                                               const float* __restrict__ n2B,
                                               const float* __restrict__ win2x,
                                               const float* __restrict__ sAf,
                                               float* __restrict__ out) {
    int i = blockIdx.x * 256 + threadIdx.x;
    float contrib = 0.f;
    if (i < LL) {
        u64 p = best[i];
        unsigned s = (unsigned)(p >> 32);
        unsigned ub = (s & 0x80000000u) ? (s & 0x7FFFFFFFu) : ~s;
        float bv = __uint_as_float(ub);
        int j = (int)(~(unsigned)(p & 0xFFFFFFFFull));
        float dot = (bv * sAf[i]) / rnB[j];
        contrib = win2x[i] + n2B[j] - 2.f * dot;
    }
    float sred = contrib;
#pragma unroll
    for (int o = 32; o > 0; o >>= 1) sred += __shfl_down(sred, o, 64);
    __shared__ float red[4];
    if ((threadIdx.x & 63) == 0) red[threadIdx.x >> 6] = sred;
    __syncthreads();
    if (threadIdx.x == 0) {
        float tot = red[0] + red[1] + red[2] + red[3];
        atomicAdd(out, tot * (1.0f / ((float)DD * (float)LL)));
    }
}

extern "C" void kernel_launch(void* const* d_in, const int* in_sizes, int n_in,
                              void* d_out, int out_size, void* d_ws, size_t ws_size,
                              hipStream_t stream) {
    const float* x  = (const float*)d_in[0];
    const float* st = (const float*)d_in[1];
    char* ws = (char*)d_ws;

    u8* Aq       = (u8*)ws;
    u8* Bq       = (u8*)(ws + OFF_BQ);
    float* rnB   = (float*)(ws + OFF_RNB);
    float* n2B   = (float*)(ws + OFF_N2B);
    float* win2x = (float*)(ws + OFF_W2X);
    float* colS  = (float*)(ws + OFF_COLS);
    float* sAf   = (float*)(ws + OFF_SAF);
    float* P2    = (float*)(ws + OFF_P2);
    float* PM    = (float*)(ws + OFF_PM);
    u64* best    = (u64*)(ws + OFF_BEST);
    float* out   = (float*)d_out;

    hipFuncSetAttribute((const void*)k_gemm2,
                        hipFuncAttributeMaxDynamicSharedMemorySize, 73728);
    hipFuncSetAttribute((const void*)k_pack,
                        hipFuncAttributeMaxDynamicSharedMemorySize, 110592);

    k_chan_stats<<<dim3(2 * NPIX / 32), dim3(256), 0, stream>>>(st, x, P2, PM,
                                                                best, out);
    k_pack<<<dim3(HO * 4), dim3(512), 108480, stream>>>(x, st, P2, PM,
                                                        rnB, n2B, win2x, colS,
                                                        sAf, Aq, Bq);
    k_gemm2<<<dim3(NTI * NTJ), dim3(512), 73728, stream>>>(Aq, Bq, colS, best);
    k_final<<<dim3(35), dim3(256), 0, stream>>>(best, rnB, n2B, win2x, sAf, out);
}